// Round 4
// baseline (64.859 us; speedup 1.0000x reference)
//
#include <hip/hip_runtime.h>
#include <hip/hip_bf16.h>

#define B_    64
#define S_    513
#define T_    512
#define H_    1024
#define OUT_  128
#define BK    32
#define NKT   (H_ / BK)   // 32
#define ROWS  96          // 64 owned + 32 margin
#define OWN   64
#define LGS   132         // logits LDS row stride (floats)

typedef __attribute__((ext_vector_type(8))) short short8_t;
typedef __attribute__((ext_vector_type(4))) float f32x4;

__device__ inline ushort f2bf(float f) {
    union { float f; unsigned u; } x; x.f = f;
    unsigned r = x.u + 0x7fffu + ((x.u >> 16) & 1u);   // RNE
    return (ushort)(r >> 16);
}
__device__ inline int4 pack8(const float4& a, const float4& b) {
    union { ushort u[8]; int4 v; } pk;
    pk.u[0] = f2bf(a.x); pk.u[1] = f2bf(a.y); pk.u[2] = f2bf(a.z); pk.u[3] = f2bf(a.w);
    pk.u[4] = f2bf(b.x); pk.u[5] = f2bf(b.y); pk.u[6] = f2bf(b.z); pk.u[7] = f2bf(b.w);
    return pk.v;
}

// ---------------------------------------------------------------------------
// Kernel 0: Wt[o][k] = bf16(W[k][o])  (256 KB, stays L2-resident)
// ---------------------------------------------------------------------------
__global__ __launch_bounds__(256) void wt_kernel(
    const float* __restrict__ W, ushort* __restrict__ Wt)
{
    __shared__ ushort tile[64][65];
    int k0 = blockIdx.x * 64, o0 = blockIdx.y * 64;
    int tid = threadIdx.x;
#pragma unroll
    for (int p = 0; p < 16; ++p) {
        int idx = tid + p * 256;
        int r = idx >> 6, c = idx & 63;
        tile[r][c] = f2bf(W[(size_t)(k0 + r) * OUT_ + o0 + c]);
    }
    __syncthreads();
#pragma unroll
    for (int p = 0; p < 16; ++p) {
        int idx = tid + p * 256;
        int c = idx >> 6, r = idx & 63;
        Wt[(size_t)(o0 + c) * H_ + k0 + r] = tile[r][c];
    }
}

// ---------------------------------------------------------------------------
// Fused: seg-info + GEMM(bf16 MFMA) + segment-mean + bias + transposed store.
// Block = (batch, 64-position tile) + dynamic margin (<=32) so every owned
// segment's full run is computed in-block. 256 thr = 4 waves (2M x 2N),
// wave tile 48x64 (3x4 frags). A: reg->bf16->LDS (linear, conflict-free
// b128). B: fragments straight from L2-resident Wt into registers.
// grid 512 = 2 blocks/CU.
// ---------------------------------------------------------------------------
__global__ __launch_bounds__(256, 2) void fused_kernel(
    const float* __restrict__ hs, const ushort* __restrict__ Wt,
    const float* __restrict__ bias, const int* __restrict__ seg,
    float* __restrict__ out)
{
    union Smem {
        ushort As[2][ROWS * BK];   // 2 x 6 KB staging
        float  lg[ROWS * LGS];     // 49.5 KB logits tile (epilogue)
    };
    __shared__ Smem sm;
    __shared__ int sseg[ROWS];
    __shared__ int lstart[OWN];
    __shared__ int lcnt[OWN];
    __shared__ int sExt, sSlo;

    int bid  = blockIdx.x;
    int b    = bid >> 3;
    int tile = bid & 7;
    int t0   = tile * OWN;
    int Tl   = (T_ - t0) < ROWS ? (T_ - t0) : ROWS;   // 96, or 64 at last tile

    int tid  = threadIdx.x;
    int lane = tid & 63;
    int w    = tid >> 6;
    int wm   = w & 1, wn = w >> 1;
    int l15  = lane & 15, ksl = lane >> 4;

    // ---- segment info -----------------------------------------------------
    if (tid < Tl)  sseg[tid] = seg[b * T_ + t0 + tid];
    if (tid < OWN) { lstart[tid] = ROWS; lcnt[tid] = 0; }
    if (tid == 0)  sExt = Tl;
    __syncthreads();
    if (tid == 0) {
        int start0 = (t0 == 0) || (seg[b * T_ + t0 - 1] != sseg[0]);
        sSlo = sseg[0] + (start0 ? 0 : 1);
    }
    if (tid >= OWN && tid < Tl && sseg[tid] != sseg[tid - 1])
        atomicMin(&sExt, tid);   // first segment start past the owned range
    __syncthreads();
    int ext  = sExt;             // rows [0, ext) are real & needed
    int s_lo = sSlo;
    int s_hi = sseg[OWN - 1] + 1;
    if (tid < ext && sseg[tid] >= s_lo) {
        int li = sseg[tid] - s_lo;                 // <= 63
        atomicMin(&lstart[li], tid);
        atomicAdd(&lcnt[li], 1);
    }
    // (lstart/lcnt consumed after K-loop barriers)

    // ---- A staging coords: thread = one 16B bf16 chunk (8 k-elems) --------
    int arow0 = tid >> 2;          // rows 0..63
    int ac    = tid & 3;           // k-chunk
    int arow1 = 64 + arow0;        // rows 64..95 (threads 0..127)
    const float* aptr0 = hs + ((size_t)(b * S_ + 1 + t0 + arow0)) * H_ + ac * 8;
    const float* aptr1 = hs + ((size_t)(b * S_ + 1 + t0 + arow1)) * H_ + ac * 8;
    bool doC1 = (tid < 128) && (arow1 < ext);
    int wA0 = arow0 * BK + ac * 8;
    int wA1 = arow1 * BK + ac * 8;

    // ---- B fragment pointers (direct global, L2-hot) ----------------------
    const ushort* bp[4];
#pragma unroll
    for (int fn = 0; fn < 4; ++fn)
        bp[fn] = Wt + (size_t)(wn * 64 + fn * 16 + l15) * H_ + ksl * 8;

    f32x4 acc[3][4];
#pragma unroll
    for (int fm = 0; fm < 3; ++fm)
#pragma unroll
        for (int fn = 0; fn < 4; ++fn) acc[fm][fn] = (f32x4){0.f, 0.f, 0.f, 0.f};

    float4 ra0, ra1, ra2, ra3;
    short8_t bfA[4], bfB[4];

    auto loadA = [&](int kt) {
        const float* p = aptr0 + kt * BK;
        ra0 = *reinterpret_cast<const float4*>(p);
        ra1 = *reinterpret_cast<const float4*>(p + 4);
        if (doC1) {
            const float* q = aptr1 + kt * BK;
            ra2 = *reinterpret_cast<const float4*>(q);
            ra3 = *reinterpret_cast<const float4*>(q + 4);
        }
    };
    auto loadB = [&](short8_t* dst, int kt) {
#pragma unroll
        for (int fn = 0; fn < 4; ++fn)
            dst[fn] = *reinterpret_cast<const short8_t*>(bp[fn] + kt * BK);
    };
    auto writeA = [&](int nb) {
        *reinterpret_cast<int4*>(&sm.As[nb][wA0]) = pack8(ra0, ra1);
        if (doC1)
            *reinterpret_cast<int4*>(&sm.As[nb][wA1]) = pack8(ra2, ra3);
    };
    auto compute = [&](int cb, short8_t* bf) {
        short8_t af[3];
#pragma unroll
        for (int fm = 0; fm < 3; ++fm)
            af[fm] = *reinterpret_cast<const short8_t*>(
                &sm.As[cb][(wm * 48 + fm * 16 + l15) * BK + ksl * 8]);
#pragma unroll
        for (int fm = 0; fm < 3; ++fm)
#pragma unroll
            for (int fn = 0; fn < 4; ++fn)
                acc[fm][fn] = __builtin_amdgcn_mfma_f32_16x16x32_bf16(
                    af[fm], bf[fn], acc[fm][fn], 0, 0, 0);
    };

    // ---- K loop (double-buffered, loads issued before compute) ------------
    loadB(bfA, 0); loadA(0);
    writeA(0);
    __syncthreads();

    for (int kt = 0; kt < NKT; kt += 2) {
        loadA(kt + 1); loadB(bfB, kt + 1);
        compute(0, bfA);
        writeA(1);
        __syncthreads();
        bool more = (kt + 2 < NKT);
        if (more) { loadA(kt + 2); loadB(bfA, kt + 2); }
        compute(1, bfB);
        if (more) writeA(0);
        __syncthreads();
    }

    // ---- epilogue: acc -> lg[t][o] (raw xW, bias added at store) -----------
#pragma unroll
    for (int fm = 0; fm < 3; ++fm) {
        int rbase = wm * 48 + fm * 16 + ksl * 4;
#pragma unroll
        for (int fn = 0; fn < 4; ++fn) {
            int o = wn * 64 + fn * 16 + l15;
#pragma unroll
            for (int r = 0; r < 4; ++r)
                sm.lg[(rbase + r) * LGS + o] = acc[fm][fn][r];
        }
    }
    __syncthreads();

    // ---- segment means + bias + transposed store ---------------------------
    int sl   = tid & 63;
    int ogrp = tid >> 6;
    int ns   = s_hi - s_lo;
    if (sl < ns) {
        int st = lstart[sl];
        int cn = lcnt[sl];
        float inv = 1.0f / (float)cn;
        float* dst = out + (size_t)b * OUT_ * T_ + s_lo + sl;
#pragma unroll 4
        for (int oi = 0; oi < 32; ++oi) {
            int o = ogrp + oi * 4;
            float sum = 0.f;
            for (int i = 0; i < cn; ++i) sum += sm.lg[(st + i) * LGS + o];
            dst[(size_t)o * T_] = sum * inv + bias[o];
        }
    }

    // last tile also zero-fills empty segment columns [s_hi, 512)
    if (tile == 7) {
        for (int o = ogrp; o < OUT_; o += 4)
            for (int s = s_hi + sl; s < T_; s += 64)
                out[((size_t)b * OUT_ + o) * T_ + s] = 0.f;
    }
}

// ---------------------------------------------------------------------------
extern "C" void kernel_launch(void* const* d_in, const int* in_sizes, int n_in,
                              void* d_out, int out_size, void* d_ws, size_t ws_size,
                              hipStream_t stream) {
    const float* hs   = (const float*)d_in[0];   // (B, S, H)
    const float* W    = (const float*)d_in[1];   // (H, OUT)
    const float* bias = (const float*)d_in[2];   // (OUT,)
    const int*   seg  = (const int*)d_in[3];     // (B, T)
    float* out = (float*)d_out;                  // (B, OUT, T)

    ushort* Wt = (ushort*)d_ws;                  // 256 KB

    wt_kernel<<<dim3(H_ / 64, OUT_ / 64), 256, 0, stream>>>(W, Wt);
    fused_kernel<<<B_ * (T_ / OWN), 256, 0, stream>>>(hs, Wt, bias, seg, out);
}